// Round 13
// baseline (640.662 us; speedup 1.0000x reference)
//
#include <hip/hip_runtime.h>
#include <math.h>

#define H 1024
#define H2 2048
#define MTOK 65536          // B*S*L = 4*2048*8

typedef __attribute__((ext_vector_type(8))) short short8;
typedef __attribute__((ext_vector_type(4))) float f32x4;

// ---------------- ws layout (bytes) ----------------
#define WS_R_OFF   0                          // 64 floats
#define WS_BS_OFF  256                        // 8 floats
#define WS_WR_OFF  4096                       // bf16 1024*1024   (2 MB)
#define WS_WG_OFF  (4096 + 2*1024*1024)       // bf16 1024*2048   (4 MB)
#define WS_RT_OFF  (8ull*1024*1024)           // bf16 MTOK*1024   (128 MB)
#define WS_XB_OFF  (WS_RT_OFF + (size_t)MTOK*H*2)   // bf16 MTOK*1024 (128 MB)
#define WS_G_OFF   (WS_XB_OFF + (size_t)MTOK*H*2)   // bf16 MTOK*1024 (128 MB)
#define WS_NEED_FULL (WS_XB_OFF + (size_t)MTOK*H*2)
#define WS_NEED_G    (WS_G_OFF  + (size_t)MTOK*H*2)

static __device__ __forceinline__ unsigned short f2bf(float f) {
    unsigned int u = __float_as_uint(f);
    u = u + 0x7fffu + ((u >> 16) & 1u);       // RNE
    return (unsigned short)(u >> 16);
}
static __device__ __forceinline__ float bf2f(unsigned short s) {
    return __uint_as_float(((unsigned int)s) << 16);
}
static __device__ __forceinline__ void gload16(const void* g, void* l) {
    __builtin_amdgcn_global_load_lds(
        (const __attribute__((address_space(1))) void*)g,
        (__attribute__((address_space(3))) void*)l, 16, 0, 0);
}

// ---------------- routing matrix ----------------
__global__ void k_routing(const float* __restrict__ lp, const float* __restrict__ thr,
                          float* __restrict__ wsR, float* __restrict__ wsBS) {
    int t = threadIdx.x;            // 0..63
    int i = t >> 3, j = t & 7;
    float mx = 0.5f * (lp[i*3+0] + lp[j*3+0]);
    float my = 0.5f * (lp[i*3+1] + lp[j*3+1]);
    float mz = 0.5f * (lp[i*3+2] + lp[j*3+2]);
    float f = sinf(mx)*cosf(my) + sinf(my)*cosf(mz) + sinf(mz)*cosf(mx) - thr[0];
    float r = 1.0f / (1.0f + expf(-2.0f * f));
    if (i == j) r = 1.0f;
    float s = r;
    s += __shfl_xor(s, 1, 64);
    s += __shfl_xor(s, 2, 64);
    s += __shfl_xor(s, 4, 64);
    float R = r / (s + 1e-6f);
    wsR[t] = R;
    if (j == 0) wsBS[i] = s / (s + 1e-6f);
}

// ---------------- fp32 -> bf16 convert ----------------
__global__ void k_f32_to_bf16(const float* __restrict__ src, unsigned short* __restrict__ dst, int n4) {
    int i = blockIdx.x * blockDim.x + threadIdx.x;
    int stride = gridDim.x * blockDim.x;
    for (; i < n4; i += stride) {
        float4 v = reinterpret_cast<const float4*>(src)[i];
        ushort4 o = make_ushort4(f2bf(v.x), f2bf(v.y), f2bf(v.z), f2bf(v.w));
        reinterpret_cast<ushort4*>(dst)[i] = o;
    }
}

// =====================================================================
// 8-phase 256x256 schedule (R8/R9, proven): counted vmcnt(4), XOR swizzle
// both-sides, LDS-bounce coalesced epilogues.
// =====================================================================

#define BAR()  __builtin_amdgcn_s_barrier()
#define SB0()  __builtin_amdgcn_sched_barrier(0)
#define WLG()  asm volatile("s_waitcnt lgkmcnt(0)" ::: "memory")

#define ASP(db, h) (&smem[((db)*2 + (h)) * 8192])
#define BSP(db, h) (&smem[32768 + ((db)*2 + (h)) * 8192])

#define MMQ(BF, mi, ni)                                                        \
    __builtin_amdgcn_s_setprio(1);                                             \
    _Pragma("unroll")                                                          \
    for (int kb = 0; kb < 2; ++kb)                                             \
    _Pragma("unroll")                                                          \
    for (int f = 0; f < 4; ++f)                                                \
    _Pragma("unroll")                                                          \
    for (int n = 0; n < 2; ++n)                                                \
        acc[(mi)+f][(ni)+n] = __builtin_amdgcn_mfma_f32_16x16x32_bf16(         \
            Af[f][kb], BF[n][kb], acc[(mi)+f][(ni)+n], 0, 0, 0);               \
    __builtin_amdgcn_s_setprio(0);

#define RD_A(qm)                                                               \
    _Pragma("unroll")                                                          \
    for (int f = 0; f < 4; ++f)                                                \
    _Pragma("unroll")                                                          \
    for (int kb = 0; kb < 2; ++kb) {                                           \
        const int r_ = (qm) + f*16 + lr;                                       \
        Af[f][kb] = *reinterpret_cast<const short8*>(                          \
            &ASP(d, ah)[r_*64 + (((kb*4 + kq) ^ sw) << 3)]);                   \
    }

#define RD_B(DST, qn)                                                          \
    _Pragma("unroll")                                                          \
    for (int f2 = 0; f2 < 2; ++f2)                                             \
    _Pragma("unroll")                                                          \
    for (int kb = 0; kb < 2; ++kb) {                                           \
        const int r_ = bo + (qn) + f2*16 + lr;                                 \
        DST[f2][kb] = *reinterpret_cast<const short8*>(                        \
            &BSP(d, bh)[r_*64 + (((kb*4 + kq) ^ sw) << 3)]);                   \
    }

// pass 1: routed = mix(xb @ Wr^T) + scale*b   (R9, unchanged)
__global__ __launch_bounds__(512, 2) void k_p1b(
    const unsigned short* __restrict__ xb,
    const unsigned short* __restrict__ Wr,
    const float* __restrict__ b_route,
    const float* __restrict__ wsR, const float* __restrict__ wsBS,
    unsigned short* __restrict__ routed)
{
    __shared__ unsigned short smem[65536];

    const int tid = threadIdx.x;
    const int l = (blockIdx.x & 7) * 128 + (blockIdx.x >> 3);
    const int bm = l >> 2, bn = l & 3;
    const int m0 = bm * 256, n0 = bn * 256;

    const int wid = tid >> 6, lane = tid & 63;
    const int ah = wid >> 2;
    const int bq = wid & 3;
    const int bh = bq >> 1;
    const int bo = (bq & 1) * 64;
    const int lr = lane & 15, kq = lane >> 4;
    const int lane8 = lane >> 3;
    const int c8s = ((lane & 7) ^ lane8) * 8;
    const int sw = lr & 7;

    f32x4 acc[8][4];
#pragma unroll
    for (int i = 0; i < 8; i++)
#pragma unroll
        for (int j = 0; j < 4; j++) acc[i][j] = (f32x4)0.0f;

#define STG_A1(db, h, t)                                                       \
    { const int _k0 = (t) * 64;                                                \
      _Pragma("unroll")                                                        \
      for (int q = 0; q < 2; ++q) {                                            \
          const int chunk = q * 8 + wid;                                       \
          gload16(xb + (size_t)(m0 + (h)*128 + chunk*8 + lane8) * H + _k0 + c8s,\
                  &ASP(db, h)[chunk * 512]);                                   \
      } }
#define STG_B1(db, h, t)                                                       \
    { const int _k0 = (t) * 64;                                                \
      _Pragma("unroll")                                                        \
      for (int q = 0; q < 2; ++q) {                                            \
          const int chunk = q * 8 + wid;                                       \
          gload16(Wr + (size_t)(n0 + (h)*128 + chunk*8 + lane8) * H + _k0 + c8s,\
                  &BSP(db, h)[chunk * 512]);                                   \
      } }

    STG_A1(0,0,0); STG_A1(0,1,0); STG_B1(0,0,0); STG_B1(0,1,0);
    STG_A1(1,0,1); STG_A1(1,1,1); STG_B1(1,0,1); STG_B1(1,1,1);
    asm volatile("s_waitcnt vmcnt(8)" ::: "memory");
    SB0();
    BAR();

    short8 Af[4][2], Bf0[2][2], Bf1[2][2];

    for (int t = 0; t < 16; ++t) {
        const int d = t & 1;
        const bool sA = (t > 0) && (t + 1 < 16);
        const bool sB = (t + 2 < 16);
        RD_A(0); RD_B(Bf0, 0);
        if (sA) { STG_A1(d^1, 0, t+1); }
        BAR(); WLG(); SB0();
        MMQ(Bf0, 0, 0);
        BAR();
        RD_B(Bf1, 32);
        if (sA) { STG_A1(d^1, 1, t+1); }
        BAR(); WLG(); SB0();
        MMQ(Bf1, 0, 2);
        BAR();
        RD_A(64);
        if (sB) { STG_B1(d, 0, t+2); }
        BAR(); WLG(); SB0();
        MMQ(Bf0, 4, 0);
        BAR();
        if (sB) { STG_B1(d, 1, t+2); }
        BAR(); SB0();
        MMQ(Bf1, 4, 2);
        if (sB)              { asm volatile("s_waitcnt vmcnt(4)" ::: "memory"); }
        else if (t + 1 < 16) { asm volatile("s_waitcnt vmcnt(0)" ::: "memory"); }
        SB0();
        BAR();
    }
#undef STG_A1
#undef STG_B1

    const int lowbit = kq & 1;
    float rc[4][8];
#pragma unroll
    for (int e = 0; e < 4; e++)
#pragma unroll
        for (int jj = 0; jj < 8; jj++) rc[e][jj] = wsR[(lowbit*4 + e)*8 + jj];
    float bsc[4];
#pragma unroll
    for (int e = 0; e < 4; e++) bsc[e] = wsBS[lowbit*4 + e];

#pragma unroll
    for (int mf = 0; mf < 8; ++mf) {
        const int lrow = ah*128 + mf*16 + kq*4;
#pragma unroll
        for (int nf = 0; nf < 4; ++nf) {
            const int lcol = bq*64 + nf*16 + lr;
            const float brv = b_route[n0 + lcol];
            float own[4], oth[4];
#pragma unroll
            for (int e = 0; e < 4; e++) {
                own[e] = acc[mf][nf][e];
                oth[e] = __shfl_xor(own[e], 16, 64);
            }
            float g8[8];
#pragma unroll
            for (int e = 0; e < 4; e++) {
                if (lowbit == 0) { g8[e] = own[e]; g8[4+e] = oth[e]; }
                else             { g8[e] = oth[e]; g8[4+e] = own[e]; }
            }
#pragma unroll
            for (int e = 0; e < 4; e++) {
                float m = 0.0f;
#pragma unroll
                for (int jj = 0; jj < 8; jj++) m += rc[e][jj] * g8[jj];
                m += bsc[e] * brv;
                smem[(lrow + e) * 256 + lcol] = f2bf(m);
            }
        }
    }
    __syncthreads();

    for (int r = wid; r < 256; r += 8) {
        const unsigned long long v =
            *reinterpret_cast<const unsigned long long*>(&smem[r*256 + lane*4]);
        *reinterpret_cast<unsigned long long*>(
            &routed[(size_t)(m0 + r) * H + n0 + lane*4]) = v;
    }
}

// pass 2 (g-split): identical loop; epilogue writes ONLY g (bf16, coalesced)
__global__ __launch_bounds__(512, 2) void k_p2g(
    const unsigned short* __restrict__ xb,
    const unsigned short* __restrict__ Wg,
    const float* __restrict__ b_gate,
    const unsigned short* __restrict__ routed,
    unsigned short* __restrict__ gout)
{
    __shared__ unsigned short smem[65536];

    const int tid = threadIdx.x;
    const int l = (blockIdx.x & 7) * 128 + (blockIdx.x >> 3);
    const int bm = l >> 2, bn = l & 3;
    const int m0 = bm * 256, n0 = bn * 256;

    const int wid = tid >> 6, lane = tid & 63;
    const int ah = wid >> 2;
    const int bq = wid & 3, bh = bq >> 1, bo = (bq & 1) * 64;
    const int lr = lane & 15, kq = lane >> 4;
    const int lane8 = lane >> 3;
    const int c8s = ((lane & 7) ^ lane8) * 8;
    const int sw = lr & 7;

    f32x4 acc[8][4];
#pragma unroll
    for (int i = 0; i < 8; i++)
#pragma unroll
        for (int j = 0; j < 4; j++) acc[i][j] = (f32x4)0.0f;

#define STG_AG(db, h, t)                                                       \
    { const int _k0 = (t) * 64;                                                \
      const unsigned short* _sb = (_k0 < H) ? xb : routed;                     \
      const int _kk = (_k0 < H) ? _k0 : (_k0 - H);                             \
      _Pragma("unroll")                                                        \
      for (int q = 0; q < 2; ++q) {                                            \
          const int chunk = q * 8 + wid;                                       \
          gload16(_sb + (size_t)(m0 + (h)*128 + chunk*8 + lane8) * H + _kk + c8s,\
                  &ASP(db, h)[chunk * 512]);                                   \
      } }
#define STG_BG(db, h, t)                                                       \
    { const int _k0 = (t) * 64;                                                \
      _Pragma("unroll")                                                        \
      for (int q = 0; q < 2; ++q) {                                            \
          const int chunk = q * 8 + wid;                                       \
          gload16(Wg + (size_t)(n0 + (h)*128 + chunk*8 + lane8) * H2 + _k0 + c8s,\
                  &BSP(db, h)[chunk * 512]);                                   \
      } }

    STG_AG(0,0,0); STG_AG(0,1,0); STG_BG(0,0,0); STG_BG(0,1,0);
    STG_AG(1,0,1); STG_AG(1,1,1); STG_BG(1,0,1); STG_BG(1,1,1);
    asm volatile("s_waitcnt vmcnt(8)" ::: "memory");
    SB0();
    BAR();

    short8 Af[4][2], Bf0[2][2], Bf1[2][2];

    for (int t = 0; t < 32; ++t) {
        const int d = t & 1;
        const bool sA = (t > 0) && (t + 1 < 32);
        const bool sB = (t + 2 < 32);
        RD_A(0); RD_B(Bf0, 0);
        if (sA) { STG_AG(d^1, 0, t+1); }
        BAR(); WLG(); SB0();
        MMQ(Bf0, 0, 0);
        BAR();
        RD_B(Bf1, 32);
        if (sA) { STG_AG(d^1, 1, t+1); }
        BAR(); WLG(); SB0();
        MMQ(Bf1, 0, 2);
        BAR();
        RD_A(64);
        if (sB) { STG_BG(d, 0, t+2); }
        BAR(); WLG(); SB0();
        MMQ(Bf0, 4, 0);
        BAR();
        if (sB) { STG_BG(d, 1, t+2); }
        BAR(); SB0();
        MMQ(Bf1, 4, 2);
        if (sB)              { asm volatile("s_waitcnt vmcnt(4)" ::: "memory"); }
        else if (t + 1 < 32) { asm volatile("s_waitcnt vmcnt(0)" ::: "memory"); }
        SB0();
        BAR();
    }
#undef STG_AG
#undef STG_BG

    // epilogue A: gate g -> smem [256][256] bf16
#pragma unroll
    for (int mf = 0; mf < 8; ++mf) {
        const int lrow = ah*128 + mf*16 + kq*4;
#pragma unroll
        for (int nf = 0; nf < 4; ++nf) {
            const int lcol = bq*64 + nf*16 + lr;
            const float bg = b_gate[n0 + lcol];
#pragma unroll
            for (int e = 0; e < 4; e++) {
                const float tt = acc[mf][nf][e] + bg;
                const float g = 1.0f / (1.0f + expf(-tt));
                smem[(lrow + e) * 256 + lcol] = f2bf(g);
            }
        }
    }
    __syncthreads();

    // epilogue B: coalesced g write ONLY (shape identical to p1b's write)
    for (int r = wid; r < 256; r += 8) {
        const unsigned long long v =
            *reinterpret_cast<const unsigned long long*>(&smem[r*256 + lane*4]);
        *reinterpret_cast<unsigned long long*>(
            &gout[(size_t)(m0 + r) * H + n0 + lane*4]) = v;
    }
}

// streaming blend: out = g*routed + (1-g)*xb  (full occupancy, nt store)
__global__ __launch_bounds__(256) void k_blend(
    const unsigned short* __restrict__ g,
    const unsigned short* __restrict__ routed,
    const unsigned short* __restrict__ xb,
    float* __restrict__ out)
{
    const size_t n8 = (size_t)MTOK * H / 8;
    size_t i = (size_t)blockIdx.x * blockDim.x + threadIdx.x;
    const size_t stride = (size_t)gridDim.x * blockDim.x;
    for (; i < n8; i += stride) {
        const uint4 gv = reinterpret_cast<const uint4*>(g)[i];
        const uint4 rv = reinterpret_cast<const uint4*>(routed)[i];
        const uint4 xv = reinterpret_cast<const uint4*>(xb)[i];
        float o[8];
        const unsigned int gw[4] = {gv.x, gv.y, gv.z, gv.w};
        const unsigned int rw[4] = {rv.x, rv.y, rv.z, rv.w};
        const unsigned int xw[4] = {xv.x, xv.y, xv.z, xv.w};
#pragma unroll
        for (int k = 0; k < 4; ++k) {
            const float g0 = bf2f((unsigned short)(gw[k] & 0xffff));
            const float g1 = bf2f((unsigned short)(gw[k] >> 16));
            o[2*k+0] = g0 * bf2f((unsigned short)(rw[k] & 0xffff))
                     + (1.0f - g0) * bf2f((unsigned short)(xw[k] & 0xffff));
            o[2*k+1] = g1 * bf2f((unsigned short)(rw[k] >> 16))
                     + (1.0f - g1) * bf2f((unsigned short)(xw[k] >> 16));
        }
        f32x4* dst = reinterpret_cast<f32x4*>(&out[i * 8]);
        f32x4 v0; v0[0] = o[0]; v0[1] = o[1]; v0[2] = o[2]; v0[3] = o[3];
        f32x4 v1; v1[0] = o[4]; v1[1] = o[5]; v1[2] = o[6]; v1[3] = o[7];
        __builtin_nontemporal_store(v0, dst);
        __builtin_nontemporal_store(v1, dst + 1);
    }
}

// pass 2 (R9 fallback tier): fused blend epilogue
__global__ __launch_bounds__(512, 2) void k_p2b(
    const unsigned short* __restrict__ xb,
    const unsigned short* __restrict__ Wg,
    const float* __restrict__ b_gate,
    const unsigned short* __restrict__ routed,
    float* __restrict__ out)
{
    __shared__ unsigned short smem[65536];

    const int tid = threadIdx.x;
    const int l = (blockIdx.x & 7) * 128 + (blockIdx.x >> 3);
    const int bm = l >> 2, bn = l & 3;
    const int m0 = bm * 256, n0 = bn * 256;

    const int wid = tid >> 6, lane = tid & 63;
    const int ah = wid >> 2;
    const int bq = wid & 3, bh = bq >> 1, bo = (bq & 1) * 64;
    const int lr = lane & 15, kq = lane >> 4;
    const int lane8 = lane >> 3;
    const int c8s = ((lane & 7) ^ lane8) * 8;
    const int sw = lr & 7;

    f32x4 acc[8][4];
#pragma unroll
    for (int i = 0; i < 8; i++)
#pragma unroll
        for (int j = 0; j < 4; j++) acc[i][j] = (f32x4)0.0f;

#define STG_A2(db, h, t)                                                       \
    { const int _k0 = (t) * 64;                                                \
      const unsigned short* _sb = (_k0 < H) ? xb : routed;                     \
      const int _kk = (_k0 < H) ? _k0 : (_k0 - H);                             \
      _Pragma("unroll")                                                        \
      for (int q = 0; q < 2; ++q) {                                            \
          const int chunk = q * 8 + wid;                                       \
          gload16(_sb + (size_t)(m0 + (h)*128 + chunk*8 + lane8) * H + _kk + c8s,\
                  &ASP(db, h)[chunk * 512]);                                   \
      } }
#define STG_B2(db, h, t)                                                       \
    { const int _k0 = (t) * 64;                                                \
      _Pragma("unroll")                                                        \
      for (int q = 0; q < 2; ++q) {                                            \
          const int chunk = q * 8 + wid;                                       \
          gload16(Wg + (size_t)(n0 + (h)*128 + chunk*8 + lane8) * H2 + _k0 + c8s,\
                  &BSP(db, h)[chunk * 512]);                                   \
      } }

    STG_A2(0,0,0); STG_A2(0,1,0); STG_B2(0,0,0); STG_B2(0,1,0);
    STG_A2(1,0,1); STG_A2(1,1,1); STG_B2(1,0,1); STG_B2(1,1,1);
    asm volatile("s_waitcnt vmcnt(8)" ::: "memory");
    SB0();
    BAR();

    short8 Af[4][2], Bf0[2][2], Bf1[2][2];

    for (int t = 0; t < 32; ++t) {
        const int d = t & 1;
        const bool sA = (t > 0) && (t + 1 < 32);
        const bool sB = (t + 2 < 32);
        RD_A(0); RD_B(Bf0, 0);
        if (sA) { STG_A2(d^1, 0, t+1); }
        BAR(); WLG(); SB0();
        MMQ(Bf0, 0, 0);
        BAR();
        RD_B(Bf1, 32);
        if (sA) { STG_A2(d^1, 1, t+1); }
        BAR(); WLG(); SB0();
        MMQ(Bf1, 0, 2);
        BAR();
        RD_A(64);
        if (sB) { STG_B2(d, 0, t+2); }
        BAR(); WLG(); SB0();
        MMQ(Bf0, 4, 0);
        BAR();
        if (sB) { STG_B2(d, 1, t+2); }
        BAR(); SB0();
        MMQ(Bf1, 4, 2);
        if (sB)              { asm volatile("s_waitcnt vmcnt(4)" ::: "memory"); }
        else if (t + 1 < 32) { asm volatile("s_waitcnt vmcnt(0)" ::: "memory"); }
        SB0();
        BAR();
    }
#undef STG_A2
#undef STG_B2

#pragma unroll
    for (int mf = 0; mf < 8; ++mf) {
        const int lrow = ah*128 + mf*16 + kq*4;
#pragma unroll
        for (int nf = 0; nf < 4; ++nf) {
            const int lcol = bq*64 + nf*16 + lr;
            const float bg = b_gate[n0 + lcol];
#pragma unroll
            for (int e = 0; e < 4; e++) {
                const float tt = acc[mf][nf][e] + bg;
                const float g = 1.0f / (1.0f + expf(-tt));
                smem[(lrow + e) * 256 + lcol] = f2bf(g);
            }
        }
    }
    __syncthreads();

    for (int r = wid; r < 256; r += 8) {
        const size_t grow = (size_t)(m0 + r) * H + n0 + lane*4;
        const ushort4 gv = *reinterpret_cast<const ushort4*>(&smem[r*256 + lane*4]);
        const ushort4 rv = *reinterpret_cast<const ushort4*>(&routed[grow]);
        const ushort4 xv = *reinterpret_cast<const ushort4*>(&xb[grow]);
        float4 o;
        {
            const float g0 = bf2f(gv.x), g1 = bf2f(gv.y), g2 = bf2f(gv.z), g3 = bf2f(gv.w);
            o.x = g0 * bf2f(rv.x) + (1.0f - g0) * bf2f(xv.x);
            o.y = g1 * bf2f(rv.y) + (1.0f - g1) * bf2f(xv.y);
            o.z = g2 * bf2f(rv.z) + (1.0f - g2) * bf2f(xv.z);
            o.w = g3 * bf2f(rv.w) + (1.0f - g3) * bf2f(xv.w);
        }
        *reinterpret_cast<float4*>(&out[grow]) = o;
    }
}

// ---------------- fallback (small ws): fully fused, fp32 vector ----------------
__global__ __launch_bounds__(256) void k_fallback(
    const float* __restrict__ x, const float* __restrict__ Wr, const float* __restrict__ br,
    const float* __restrict__ Wg, const float* __restrict__ bg,
    const float* __restrict__ wsR, const float* __restrict__ wsBS,
    float* __restrict__ out)
{
    __shared__ float xs[8][H];
    __shared__ float rt[8][H];
    __shared__ float Rs[64];
    __shared__ float BSs[8];

    const int tid = threadIdx.x;
    const size_t base = (size_t)blockIdx.x * (8 * H);
    if (tid < 64) Rs[tid] = wsR[tid];
    if (tid < 8)  BSs[tid] = wsBS[tid];

#pragma unroll
    for (int it = 0; it < 8; ++it) {
        int s = it * 256 + tid;
        reinterpret_cast<float4*>(&xs[0][0])[s] = reinterpret_cast<const float4*>(x + base)[s];
    }
    __syncthreads();

    for (int eo = 0; eo < 4; ++eo) {
        int e = eo * 256 + tid;
        float acc[8];
#pragma unroll
        for (int l = 0; l < 8; l++) acc[l] = 0.0f;
        const float* w = Wr + (size_t)e * H;
        for (int k = 0; k < H; k += 4) {
            float4 wv = *reinterpret_cast<const float4*>(w + k);
#pragma unroll
            for (int l = 0; l < 8; l++)
                acc[l] += wv.x * xs[l][k] + wv.y * xs[l][k+1] + wv.z * xs[l][k+2] + wv.w * xs[l][k+3];
        }
        float brv = br[e];
#pragma unroll
        for (int l = 0; l < 8; l++) {
            float m = 0.0f;
#pragma unroll
            for (int j = 0; j < 8; j++) m += Rs[l*8 + j] * acc[j];
            rt[l][e] = m + BSs[l] * brv;
        }
    }
    __syncthreads();

    for (int eo = 0; eo < 4; ++eo) {
        int e = eo * 256 + tid;
        float acc2[8];
#pragma unroll
        for (int l = 0; l < 8; l++) acc2[l] = 0.0f;
        const float* w1 = Wg + (size_t)e * (2 * H);
        for (int k = 0; k < H; k += 4) {
            float4 wv = *reinterpret_cast<const float4*>(w1 + k);
#pragma unroll
            for (int l = 0; l < 8; l++)
                acc2[l] += wv.x * xs[l][k] + wv.y * xs[l][k+1] + wv.z * xs[l][k+2] + wv.w * xs[l][k+3];
        }
        const float* w2 = w1 + H;
        for (int k = 0; k < H; k += 4) {
            float4 wv = *reinterpret_cast<const float4*>(w2 + k);
#pragma unroll
            for (int l = 0; l < 8; l++)
                acc2[l] += wv.x * rt[l][k] + wv.y * rt[l][k+1] + wv.z * rt[l][k+2] + wv.w * rt[l][k+3];
        }
        float bgv = bg[e];
#pragma unroll
        for (int l = 0; l < 8; l++) {
            float t = acc2[l] + bgv;
            float g = 1.0f / (1.0f + expf(-t));
            out[base + (size_t)l * H + e] = g * rt[l][e] + (1.0f - g) * xs[l][e];
        }
    }
}

extern "C" void kernel_launch(void* const* d_in, const int* in_sizes, int n_in,
                              void* d_out, int out_size, void* d_ws, size_t ws_size,
                              hipStream_t stream) {
    const float* x   = (const float*)d_in[0];
    const float* lp  = (const float*)d_in[1];
    const float* thr = (const float*)d_in[2];
    const float* Wr  = (const float*)d_in[3];
    const float* br  = (const float*)d_in[4];
    const float* Wg  = (const float*)d_in[5];
    const float* bg  = (const float*)d_in[6];
    float* out = (float*)d_out;
    char* ws = (char*)d_ws;

    float* wsR  = (float*)(ws + WS_R_OFF);
    float* wsBS = (float*)(ws + WS_BS_OFF);

    k_routing<<<1, 64, 0, stream>>>(lp, thr, wsR, wsBS);

    if (ws_size >= WS_NEED_G) {
        unsigned short* wsWr = (unsigned short*)(ws + WS_WR_OFF);
        unsigned short* wsWg = (unsigned short*)(ws + WS_WG_OFF);
        unsigned short* wsRt = (unsigned short*)(ws + WS_RT_OFF);
        unsigned short* wsXb = (unsigned short*)(ws + WS_XB_OFF);
        unsigned short* wsG  = (unsigned short*)(ws + WS_G_OFF);
        k_f32_to_bf16<<<512, 256, 0, stream>>>(Wr, wsWr, (1024 * 1024) / 4);
        k_f32_to_bf16<<<1024, 256, 0, stream>>>(Wg, wsWg, (1024 * 2048) / 4);
        k_f32_to_bf16<<<4096, 256, 0, stream>>>(x, wsXb, (MTOK * H) / 4);
        k_p1b<<<(MTOK / 256) * (H / 256), 512, 0, stream>>>(wsXb, wsWr, br, wsR, wsBS, wsRt);
        k_p2g<<<(MTOK / 256) * (H / 256), 512, 0, stream>>>(wsXb, wsWg, bg, wsRt, wsG);
        k_blend<<<2048, 256, 0, stream>>>(wsG, wsRt, wsXb, out);
    } else if (ws_size >= WS_NEED_FULL) {
        unsigned short* wsWr = (unsigned short*)(ws + WS_WR_OFF);
        unsigned short* wsWg = (unsigned short*)(ws + WS_WG_OFF);
        unsigned short* wsRt = (unsigned short*)(ws + WS_RT_OFF);
        unsigned short* wsXb = (unsigned short*)(ws + WS_XB_OFF);
        k_f32_to_bf16<<<512, 256, 0, stream>>>(Wr, wsWr, (1024 * 1024) / 4);
        k_f32_to_bf16<<<1024, 256, 0, stream>>>(Wg, wsWg, (1024 * 2048) / 4);
        k_f32_to_bf16<<<4096, 256, 0, stream>>>(x, wsXb, (MTOK * H) / 4);
        k_p1b<<<(MTOK / 256) * (H / 256), 512, 0, stream>>>(wsXb, wsWr, br, wsR, wsBS, wsRt);
        k_p2b<<<(MTOK / 256) * (H / 256), 512, 0, stream>>>(wsXb, wsWg, bg, wsRt, out);
    } else {
        k_fallback<<<MTOK / 8, 256, 0, stream>>>(x, Wr, br, Wg, bg, wsR, wsBS, out);
    }
}

// Round 14
// 554.010 us; speedup vs baseline: 1.1564x; 1.1564x over previous
//
#include <hip/hip_runtime.h>
#include <math.h>

#define H 1024
#define H2 2048
#define MTOK 65536          // B*S*L = 4*2048*8

typedef __attribute__((ext_vector_type(8))) short short8;
typedef __attribute__((ext_vector_type(4))) float f32x4;
typedef __attribute__((ext_vector_type(4))) unsigned short u16x4;

// ---------------- ws layout (bytes) ----------------
#define WS_R_OFF   0                          // 64 floats
#define WS_BS_OFF  256                        // 8 floats
#define WS_WR_OFF  4096                       // bf16 1024*1024   (2 MB)
#define WS_WG_OFF  (4096 + 2*1024*1024)       // bf16 1024*2048   (4 MB)
#define WS_RT_OFF  (8ull*1024*1024)           // bf16 MTOK*1024   (128 MB)
#define WS_XB_OFF  (WS_RT_OFF + (size_t)MTOK*H*2)   // bf16 MTOK*1024 (128 MB)
#define WS_NEED_FULL (WS_XB_OFF + (size_t)MTOK*H*2)

static __device__ __forceinline__ unsigned short f2bf(float f) {
    unsigned int u = __float_as_uint(f);
    u = u + 0x7fffu + ((u >> 16) & 1u);       // RNE
    return (unsigned short)(u >> 16);
}
static __device__ __forceinline__ float bf2f(unsigned short s) {
    return __uint_as_float(((unsigned int)s) << 16);
}
static __device__ __forceinline__ void gload16(const void* g, void* l) {
    __builtin_amdgcn_global_load_lds(
        (const __attribute__((address_space(1))) void*)g,
        (__attribute__((address_space(3))) void*)l, 16, 0, 0);
}

// ---------------- routing matrix ----------------
__global__ void k_routing(const float* __restrict__ lp, const float* __restrict__ thr,
                          float* __restrict__ wsR, float* __restrict__ wsBS) {
    int t = threadIdx.x;            // 0..63
    int i = t >> 3, j = t & 7;
    float mx = 0.5f * (lp[i*3+0] + lp[j*3+0]);
    float my = 0.5f * (lp[i*3+1] + lp[j*3+1]);
    float mz = 0.5f * (lp[i*3+2] + lp[j*3+2]);
    float f = sinf(mx)*cosf(my) + sinf(my)*cosf(mz) + sinf(mz)*cosf(mx) - thr[0];
    float r = 1.0f / (1.0f + expf(-2.0f * f));
    if (i == j) r = 1.0f;
    float s = r;
    s += __shfl_xor(s, 1, 64);
    s += __shfl_xor(s, 2, 64);
    s += __shfl_xor(s, 4, 64);
    float R = r / (s + 1e-6f);
    wsR[t] = R;
    if (j == 0) wsBS[i] = s / (s + 1e-6f);
}

// ---------------- fp32 -> bf16 convert ----------------
__global__ void k_f32_to_bf16(const float* __restrict__ src, unsigned short* __restrict__ dst, int n4) {
    int i = blockIdx.x * blockDim.x + threadIdx.x;
    int stride = gridDim.x * blockDim.x;
    for (; i < n4; i += stride) {
        float4 v = reinterpret_cast<const float4*>(src)[i];
        ushort4 o = make_ushort4(f2bf(v.x), f2bf(v.y), f2bf(v.z), f2bf(v.w));
        reinterpret_cast<ushort4*>(dst)[i] = o;
    }
}

// =====================================================================
// 8-phase 256x256 schedule (R8/R9, proven): counted vmcnt(4), XOR swizzle
// both-sides, LDS-bounce coalesced epilogues.  R14: non-temporal writes
// for routed (p1b) and out (p2b) to keep L2 clean across passes.
// =====================================================================

#define BAR()  __builtin_amdgcn_s_barrier()
#define SB0()  __builtin_amdgcn_sched_barrier(0)
#define WLG()  asm volatile("s_waitcnt lgkmcnt(0)" ::: "memory")

#define ASP(db, h) (&smem[((db)*2 + (h)) * 8192])
#define BSP(db, h) (&smem[32768 + ((db)*2 + (h)) * 8192])

#define MMQ(BF, mi, ni)                                                        \
    __builtin_amdgcn_s_setprio(1);                                             \
    _Pragma("unroll")                                                          \
    for (int kb = 0; kb < 2; ++kb)                                             \
    _Pragma("unroll")                                                          \
    for (int f = 0; f < 4; ++f)                                                \
    _Pragma("unroll")                                                          \
    for (int n = 0; n < 2; ++n)                                                \
        acc[(mi)+f][(ni)+n] = __builtin_amdgcn_mfma_f32_16x16x32_bf16(         \
            Af[f][kb], BF[n][kb], acc[(mi)+f][(ni)+n], 0, 0, 0);               \
    __builtin_amdgcn_s_setprio(0);

#define RD_A(qm)                                                               \
    _Pragma("unroll")                                                          \
    for (int f = 0; f < 4; ++f)                                                \
    _Pragma("unroll")                                                          \
    for (int kb = 0; kb < 2; ++kb) {                                           \
        const int r_ = (qm) + f*16 + lr;                                       \
        Af[f][kb] = *reinterpret_cast<const short8*>(                          \
            &ASP(d, ah)[r_*64 + (((kb*4 + kq) ^ sw) << 3)]);                   \
    }

#define RD_B(DST, qn)                                                          \
    _Pragma("unroll")                                                          \
    for (int f2 = 0; f2 < 2; ++f2)                                             \
    _Pragma("unroll")                                                          \
    for (int kb = 0; kb < 2; ++kb) {                                           \
        const int r_ = bo + (qn) + f2*16 + lr;                                 \
        DST[f2][kb] = *reinterpret_cast<const short8*>(                        \
            &BSP(d, bh)[r_*64 + (((kb*4 + kq) ^ sw) << 3)]);                   \
    }

// pass 1: routed = mix(xb @ Wr^T) + scale*b
__global__ __launch_bounds__(512, 2) void k_p1b(
    const unsigned short* __restrict__ xb,
    const unsigned short* __restrict__ Wr,
    const float* __restrict__ b_route,
    const float* __restrict__ wsR, const float* __restrict__ wsBS,
    unsigned short* __restrict__ routed)
{
    __shared__ unsigned short smem[65536];

    const int tid = threadIdx.x;
    const int l = (blockIdx.x & 7) * 128 + (blockIdx.x >> 3);
    const int bm = l >> 2, bn = l & 3;
    const int m0 = bm * 256, n0 = bn * 256;

    const int wid = tid >> 6, lane = tid & 63;
    const int ah = wid >> 2;
    const int bq = wid & 3;
    const int bh = bq >> 1;
    const int bo = (bq & 1) * 64;
    const int lr = lane & 15, kq = lane >> 4;
    const int lane8 = lane >> 3;
    const int c8s = ((lane & 7) ^ lane8) * 8;
    const int sw = lr & 7;

    f32x4 acc[8][4];
#pragma unroll
    for (int i = 0; i < 8; i++)
#pragma unroll
        for (int j = 0; j < 4; j++) acc[i][j] = (f32x4)0.0f;

#define STG_A1(db, h, t)                                                       \
    { const int _k0 = (t) * 64;                                                \
      _Pragma("unroll")                                                        \
      for (int q = 0; q < 2; ++q) {                                            \
          const int chunk = q * 8 + wid;                                       \
          gload16(xb + (size_t)(m0 + (h)*128 + chunk*8 + lane8) * H + _k0 + c8s,\
                  &ASP(db, h)[chunk * 512]);                                   \
      } }
#define STG_B1(db, h, t)                                                       \
    { const int _k0 = (t) * 64;                                                \
      _Pragma("unroll")                                                        \
      for (int q = 0; q < 2; ++q) {                                            \
          const int chunk = q * 8 + wid;                                       \
          gload16(Wr + (size_t)(n0 + (h)*128 + chunk*8 + lane8) * H + _k0 + c8s,\
                  &BSP(db, h)[chunk * 512]);                                   \
      } }

    STG_A1(0,0,0); STG_A1(0,1,0); STG_B1(0,0,0); STG_B1(0,1,0);
    STG_A1(1,0,1); STG_A1(1,1,1); STG_B1(1,0,1); STG_B1(1,1,1);
    asm volatile("s_waitcnt vmcnt(8)" ::: "memory");
    SB0();
    BAR();

    short8 Af[4][2], Bf0[2][2], Bf1[2][2];

    for (int t = 0; t < 16; ++t) {
        const int d = t & 1;
        const bool sA = (t > 0) && (t + 1 < 16);
        const bool sB = (t + 2 < 16);
        RD_A(0); RD_B(Bf0, 0);
        if (sA) { STG_A1(d^1, 0, t+1); }
        BAR(); WLG(); SB0();
        MMQ(Bf0, 0, 0);
        BAR();
        RD_B(Bf1, 32);
        if (sA) { STG_A1(d^1, 1, t+1); }
        BAR(); WLG(); SB0();
        MMQ(Bf1, 0, 2);
        BAR();
        RD_A(64);
        if (sB) { STG_B1(d, 0, t+2); }
        BAR(); WLG(); SB0();
        MMQ(Bf0, 4, 0);
        BAR();
        if (sB) { STG_B1(d, 1, t+2); }
        BAR(); SB0();
        MMQ(Bf1, 4, 2);
        if (sB)              { asm volatile("s_waitcnt vmcnt(4)" ::: "memory"); }
        else if (t + 1 < 16) { asm volatile("s_waitcnt vmcnt(0)" ::: "memory"); }
        SB0();
        BAR();
    }
#undef STG_A1
#undef STG_B1

    const int lowbit = kq & 1;
    float rc[4][8];
#pragma unroll
    for (int e = 0; e < 4; e++)
#pragma unroll
        for (int jj = 0; jj < 8; jj++) rc[e][jj] = wsR[(lowbit*4 + e)*8 + jj];
    float bsc[4];
#pragma unroll
    for (int e = 0; e < 4; e++) bsc[e] = wsBS[lowbit*4 + e];

#pragma unroll
    for (int mf = 0; mf < 8; ++mf) {
        const int lrow = ah*128 + mf*16 + kq*4;
#pragma unroll
        for (int nf = 0; nf < 4; ++nf) {
            const int lcol = bq*64 + nf*16 + lr;
            const float brv = b_route[n0 + lcol];
            float own[4], oth[4];
#pragma unroll
            for (int e = 0; e < 4; e++) {
                own[e] = acc[mf][nf][e];
                oth[e] = __shfl_xor(own[e], 16, 64);
            }
            float g8[8];
#pragma unroll
            for (int e = 0; e < 4; e++) {
                if (lowbit == 0) { g8[e] = own[e]; g8[4+e] = oth[e]; }
                else             { g8[e] = oth[e]; g8[4+e] = own[e]; }
            }
#pragma unroll
            for (int e = 0; e < 4; e++) {
                float m = 0.0f;
#pragma unroll
                for (int jj = 0; jj < 8; jj++) m += rc[e][jj] * g8[jj];
                m += bsc[e] * brv;
                smem[(lrow + e) * 256 + lcol] = f2bf(m);
            }
        }
    }
    __syncthreads();

    // coalesced non-temporal write of routed (keep L2 clean for pass 2)
    for (int r = wid; r < 256; r += 8) {
        const u16x4 v = *reinterpret_cast<const u16x4*>(&smem[r*256 + lane*4]);
        __builtin_nontemporal_store(v,
            reinterpret_cast<u16x4*>(&routed[(size_t)(m0 + r) * H + n0 + lane*4]));
    }
}

// pass 2: out = g*routed + (1-g)*x,  g = sigmoid([xb|routed] @ Wg^T + b)
__global__ __launch_bounds__(512, 2) void k_p2b(
    const unsigned short* __restrict__ xb,
    const unsigned short* __restrict__ Wg,
    const float* __restrict__ b_gate,
    const unsigned short* __restrict__ routed,
    float* __restrict__ out)
{
    __shared__ unsigned short smem[65536];

    const int tid = threadIdx.x;
    const int l = (blockIdx.x & 7) * 128 + (blockIdx.x >> 3);
    const int bm = l >> 2, bn = l & 3;
    const int m0 = bm * 256, n0 = bn * 256;

    const int wid = tid >> 6, lane = tid & 63;
    const int ah = wid >> 2;
    const int bq = wid & 3, bh = bq >> 1, bo = (bq & 1) * 64;
    const int lr = lane & 15, kq = lane >> 4;
    const int lane8 = lane >> 3;
    const int c8s = ((lane & 7) ^ lane8) * 8;
    const int sw = lr & 7;

    f32x4 acc[8][4];
#pragma unroll
    for (int i = 0; i < 8; i++)
#pragma unroll
        for (int j = 0; j < 4; j++) acc[i][j] = (f32x4)0.0f;

#define STG_A2(db, h, t)                                                       \
    { const int _k0 = (t) * 64;                                                \
      const unsigned short* _sb = (_k0 < H) ? xb : routed;                     \
      const int _kk = (_k0 < H) ? _k0 : (_k0 - H);                             \
      _Pragma("unroll")                                                        \
      for (int q = 0; q < 2; ++q) {                                            \
          const int chunk = q * 8 + wid;                                       \
          gload16(_sb + (size_t)(m0 + (h)*128 + chunk*8 + lane8) * H + _kk + c8s,\
                  &ASP(db, h)[chunk * 512]);                                   \
      } }
#define STG_B2(db, h, t)                                                       \
    { const int _k0 = (t) * 64;                                                \
      _Pragma("unroll")                                                        \
      for (int q = 0; q < 2; ++q) {                                            \
          const int chunk = q * 8 + wid;                                       \
          gload16(Wg + (size_t)(n0 + (h)*128 + chunk*8 + lane8) * H2 + _k0 + c8s,\
                  &BSP(db, h)[chunk * 512]);                                   \
      } }

    STG_A2(0,0,0); STG_A2(0,1,0); STG_B2(0,0,0); STG_B2(0,1,0);
    STG_A2(1,0,1); STG_A2(1,1,1); STG_B2(1,0,1); STG_B2(1,1,1);
    asm volatile("s_waitcnt vmcnt(8)" ::: "memory");
    SB0();
    BAR();

    short8 Af[4][2], Bf0[2][2], Bf1[2][2];

    for (int t = 0; t < 32; ++t) {
        const int d = t & 1;
        const bool sA = (t > 0) && (t + 1 < 32);
        const bool sB = (t + 2 < 32);
        RD_A(0); RD_B(Bf0, 0);
        if (sA) { STG_A2(d^1, 0, t+1); }
        BAR(); WLG(); SB0();
        MMQ(Bf0, 0, 0);
        BAR();
        RD_B(Bf1, 32);
        if (sA) { STG_A2(d^1, 1, t+1); }
        BAR(); WLG(); SB0();
        MMQ(Bf1, 0, 2);
        BAR();
        RD_A(64);
        if (sB) { STG_B2(d, 0, t+2); }
        BAR(); WLG(); SB0();
        MMQ(Bf0, 4, 0);
        BAR();
        if (sB) { STG_B2(d, 1, t+2); }
        BAR(); SB0();
        MMQ(Bf1, 4, 2);
        if (sB)              { asm volatile("s_waitcnt vmcnt(4)" ::: "memory"); }
        else if (t + 1 < 32) { asm volatile("s_waitcnt vmcnt(0)" ::: "memory"); }
        SB0();
        BAR();
    }
#undef STG_A2
#undef STG_B2

#pragma unroll
    for (int mf = 0; mf < 8; ++mf) {
        const int lrow = ah*128 + mf*16 + kq*4;
#pragma unroll
        for (int nf = 0; nf < 4; ++nf) {
            const int lcol = bq*64 + nf*16 + lr;
            const float bg = b_gate[n0 + lcol];
#pragma unroll
            for (int e = 0; e < 4; e++) {
                const float tt = acc[mf][nf][e] + bg;
                const float g = 1.0f / (1.0f + expf(-tt));
                smem[(lrow + e) * 256 + lcol] = f2bf(g);
            }
        }
    }
    __syncthreads();

    // coalesced blend sweep; out written non-temporally (pure stream)
    for (int r = wid; r < 256; r += 8) {
        const size_t grow = (size_t)(m0 + r) * H + n0 + lane*4;
        const ushort4 gv = *reinterpret_cast<const ushort4*>(&smem[r*256 + lane*4]);
        const ushort4 rv = *reinterpret_cast<const ushort4*>(&routed[grow]);
        const ushort4 xv = *reinterpret_cast<const ushort4*>(&xb[grow]);
        f32x4 o;
        {
            const float g0 = bf2f(gv.x), g1 = bf2f(gv.y), g2 = bf2f(gv.z), g3 = bf2f(gv.w);
            o[0] = g0 * bf2f(rv.x) + (1.0f - g0) * bf2f(xv.x);
            o[1] = g1 * bf2f(rv.y) + (1.0f - g1) * bf2f(xv.y);
            o[2] = g2 * bf2f(rv.z) + (1.0f - g2) * bf2f(xv.z);
            o[3] = g3 * bf2f(rv.w) + (1.0f - g3) * bf2f(xv.w);
        }
        __builtin_nontemporal_store(o, reinterpret_cast<f32x4*>(&out[grow]));
    }
}

// ---------------- fallback (small ws): fully fused, fp32 vector ----------------
__global__ __launch_bounds__(256) void k_fallback(
    const float* __restrict__ x, const float* __restrict__ Wr, const float* __restrict__ br,
    const float* __restrict__ Wg, const float* __restrict__ bg,
    const float* __restrict__ wsR, const float* __restrict__ wsBS,
    float* __restrict__ out)
{
    __shared__ float xs[8][H];
    __shared__ float rt[8][H];
    __shared__ float Rs[64];
    __shared__ float BSs[8];

    const int tid = threadIdx.x;
    const size_t base = (size_t)blockIdx.x * (8 * H);
    if (tid < 64) Rs[tid] = wsR[tid];
    if (tid < 8)  BSs[tid] = wsBS[tid];

#pragma unroll
    for (int it = 0; it < 8; ++it) {
        int s = it * 256 + tid;
        reinterpret_cast<float4*>(&xs[0][0])[s] = reinterpret_cast<const float4*>(x + base)[s];
    }
    __syncthreads();

    for (int eo = 0; eo < 4; ++eo) {
        int e = eo * 256 + tid;
        float acc[8];
#pragma unroll
        for (int l = 0; l < 8; l++) acc[l] = 0.0f;
        const float* w = Wr + (size_t)e * H;
        for (int k = 0; k < H; k += 4) {
            float4 wv = *reinterpret_cast<const float4*>(w + k);
#pragma unroll
            for (int l = 0; l < 8; l++)
                acc[l] += wv.x * xs[l][k] + wv.y * xs[l][k+1] + wv.z * xs[l][k+2] + wv.w * xs[l][k+3];
        }
        float brv = br[e];
#pragma unroll
        for (int l = 0; l < 8; l++) {
            float m = 0.0f;
#pragma unroll
            for (int j = 0; j < 8; j++) m += Rs[l*8 + j] * acc[j];
            rt[l][e] = m + BSs[l] * brv;
        }
    }
    __syncthreads();

    for (int eo = 0; eo < 4; ++eo) {
        int e = eo * 256 + tid;
        float acc2[8];
#pragma unroll
        for (int l = 0; l < 8; l++) acc2[l] = 0.0f;
        const float* w1 = Wg + (size_t)e * (2 * H);
        for (int k = 0; k < H; k += 4) {
            float4 wv = *reinterpret_cast<const float4*>(w1 + k);
#pragma unroll
            for (int l = 0; l < 8; l++)
                acc2[l] += wv.x * xs[l][k] + wv.y * xs[l][k+1] + wv.z * xs[l][k+2] + wv.w * xs[l][k+3];
        }
        const float* w2 = w1 + H;
        for (int k = 0; k < H; k += 4) {
            float4 wv = *reinterpret_cast<const float4*>(w2 + k);
#pragma unroll
            for (int l = 0; l < 8; l++)
                acc2[l] += wv.x * rt[l][k] + wv.y * rt[l][k+1] + wv.z * rt[l][k+2] + wv.w * rt[l][k+3];
        }
        float bgv = bg[e];
#pragma unroll
        for (int l = 0; l < 8; l++) {
            float t = acc2[l] + bgv;
            float g = 1.0f / (1.0f + expf(-t));
            out[base + (size_t)l * H + e] = g * rt[l][e] + (1.0f - g) * xs[l][e];
        }
    }
}

extern "C" void kernel_launch(void* const* d_in, const int* in_sizes, int n_in,
                              void* d_out, int out_size, void* d_ws, size_t ws_size,
                              hipStream_t stream) {
    const float* x   = (const float*)d_in[0];
    const float* lp  = (const float*)d_in[1];
    const float* thr = (const float*)d_in[2];
    const float* Wr  = (const float*)d_in[3];
    const float* br  = (const float*)d_in[4];
    const float* Wg  = (const float*)d_in[5];
    const float* bg  = (const float*)d_in[6];
    float* out = (float*)d_out;
    char* ws = (char*)d_ws;

    float* wsR  = (float*)(ws + WS_R_OFF);
    float* wsBS = (float*)(ws + WS_BS_OFF);

    k_routing<<<1, 64, 0, stream>>>(lp, thr, wsR, wsBS);

    if (ws_size >= WS_NEED_FULL) {
        unsigned short* wsWr = (unsigned short*)(ws + WS_WR_OFF);
        unsigned short* wsWg = (unsigned short*)(ws + WS_WG_OFF);
        unsigned short* wsRt = (unsigned short*)(ws + WS_RT_OFF);
        unsigned short* wsXb = (unsigned short*)(ws + WS_XB_OFF);
        k_f32_to_bf16<<<512, 256, 0, stream>>>(Wr, wsWr, (1024 * 1024) / 4);
        k_f32_to_bf16<<<1024, 256, 0, stream>>>(Wg, wsWg, (1024 * 2048) / 4);
        k_f32_to_bf16<<<4096, 256, 0, stream>>>(x, wsXb, (MTOK * H) / 4);
        k_p1b<<<(MTOK / 256) * (H / 256), 512, 0, stream>>>(wsXb, wsWr, br, wsR, wsBS, wsRt);
        k_p2b<<<(MTOK / 256) * (H / 256), 512, 0, stream>>>(wsXb, wsWg, bg, wsRt, out);
    } else {
        k_fallback<<<MTOK / 8, 256, 0, stream>>>(x, Wr, br, Wg, bg, wsR, wsBS, out);
    }
}

// Round 15
// 551.623 us; speedup vs baseline: 1.1614x; 1.0043x over previous
//
#include <hip/hip_runtime.h>
#include <math.h>

#define H 1024
#define H2 2048
#define MTOK 65536          // B*S*L = 4*2048*8

typedef __attribute__((ext_vector_type(8))) short short8;
typedef __attribute__((ext_vector_type(4))) float f32x4;
typedef __attribute__((ext_vector_type(4))) unsigned short u16x4;

// ---------------- ws layout (bytes) ----------------
#define WS_R_OFF   0                          // 64 floats
#define WS_BS_OFF  256                        // 8 floats
#define WS_WR_OFF  4096                       // bf16 1024*1024   (2 MB)
#define WS_WG_OFF  (4096 + 2*1024*1024)       // bf16 1024*2048   (4 MB)
#define WS_RT_OFF  (8ull*1024*1024)           // bf16 MTOK*1024   (128 MB)
#define WS_XB_OFF  (WS_RT_OFF + (size_t)MTOK*H*2)   // bf16 MTOK*1024 (128 MB)
#define WS_NEED_FULL (WS_XB_OFF + (size_t)MTOK*H*2)

static __device__ __forceinline__ unsigned short f2bf(float f) {
    unsigned int u = __float_as_uint(f);
    u = u + 0x7fffu + ((u >> 16) & 1u);       // RNE
    return (unsigned short)(u >> 16);
}
static __device__ __forceinline__ float bf2f(unsigned short s) {
    return __uint_as_float(((unsigned int)s) << 16);
}
static __device__ __forceinline__ void gload16(const void* g, void* l) {
    __builtin_amdgcn_global_load_lds(
        (const __attribute__((address_space(1))) void*)g,
        (__attribute__((address_space(3))) void*)l, 16, 0, 0);
}

// ---------------- routing matrix ----------------
__global__ void k_routing(const float* __restrict__ lp, const float* __restrict__ thr,
                          float* __restrict__ wsR, float* __restrict__ wsBS) {
    int t = threadIdx.x;            // 0..63
    int i = t >> 3, j = t & 7;
    float mx = 0.5f * (lp[i*3+0] + lp[j*3+0]);
    float my = 0.5f * (lp[i*3+1] + lp[j*3+1]);
    float mz = 0.5f * (lp[i*3+2] + lp[j*3+2]);
    float f = sinf(mx)*cosf(my) + sinf(my)*cosf(mz) + sinf(mz)*cosf(mx) - thr[0];
    float r = 1.0f / (1.0f + expf(-2.0f * f));
    if (i == j) r = 1.0f;
    float s = r;
    s += __shfl_xor(s, 1, 64);
    s += __shfl_xor(s, 2, 64);
    s += __shfl_xor(s, 4, 64);
    float R = r / (s + 1e-6f);
    wsR[t] = R;
    if (j == 0) wsBS[i] = s / (s + 1e-6f);
}

// ---------------- fp32 -> bf16 convert (nt store: clean lines for GEMM stages) ----------------
__global__ void k_f32_to_bf16(const float* __restrict__ src, unsigned short* __restrict__ dst, int n4) {
    int i = blockIdx.x * blockDim.x + threadIdx.x;
    int stride = gridDim.x * blockDim.x;
    for (; i < n4; i += stride) {
        float4 v = reinterpret_cast<const float4*>(src)[i];
        u16x4 o;
        o[0] = f2bf(v.x); o[1] = f2bf(v.y); o[2] = f2bf(v.z); o[3] = f2bf(v.w);
        __builtin_nontemporal_store(o, reinterpret_cast<u16x4*>(dst) + i);
    }
}

// =====================================================================
// 8-phase 256x256 schedule (R8/R9, proven): counted vmcnt(4), XOR swizzle
// both-sides, LDS-bounce coalesced epilogues.  R14: nt writes for routed /
// out.  R15: nt store for xb convert; nt loads in p2b blend sweep.
// =====================================================================

#define BAR()  __builtin_amdgcn_s_barrier()
#define SB0()  __builtin_amdgcn_sched_barrier(0)
#define WLG()  asm volatile("s_waitcnt lgkmcnt(0)" ::: "memory")

#define ASP(db, h) (&smem[((db)*2 + (h)) * 8192])
#define BSP(db, h) (&smem[32768 + ((db)*2 + (h)) * 8192])

#define MMQ(BF, mi, ni)                                                        \
    __builtin_amdgcn_s_setprio(1);                                             \
    _Pragma("unroll")                                                          \
    for (int kb = 0; kb < 2; ++kb)                                             \
    _Pragma("unroll")                                                          \
    for (int f = 0; f < 4; ++f)                                                \
    _Pragma("unroll")                                                          \
    for (int n = 0; n < 2; ++n)                                                \
        acc[(mi)+f][(ni)+n] = __builtin_amdgcn_mfma_f32_16x16x32_bf16(         \
            Af[f][kb], BF[n][kb], acc[(mi)+f][(ni)+n], 0, 0, 0);               \
    __builtin_amdgcn_s_setprio(0);

#define RD_A(qm)                                                               \
    _Pragma("unroll")                                                          \
    for (int f = 0; f < 4; ++f)                                                \
    _Pragma("unroll")                                                          \
    for (int kb = 0; kb < 2; ++kb) {                                           \
        const int r_ = (qm) + f*16 + lr;                                       \
        Af[f][kb] = *reinterpret_cast<const short8*>(                          \
            &ASP(d, ah)[r_*64 + (((kb*4 + kq) ^ sw) << 3)]);                   \
    }

#define RD_B(DST, qn)                                                          \
    _Pragma("unroll")                                                          \
    for (int f2 = 0; f2 < 2; ++f2)                                             \
    _Pragma("unroll")                                                          \
    for (int kb = 0; kb < 2; ++kb) {                                           \
        const int r_ = bo + (qn) + f2*16 + lr;                                 \
        DST[f2][kb] = *reinterpret_cast<const short8*>(                        \
            &BSP(d, bh)[r_*64 + (((kb*4 + kq) ^ sw) << 3)]);                   \
    }

// pass 1: routed = mix(xb @ Wr^T) + scale*b
__global__ __launch_bounds__(512, 2) void k_p1b(
    const unsigned short* __restrict__ xb,
    const unsigned short* __restrict__ Wr,
    const float* __restrict__ b_route,
    const float* __restrict__ wsR, const float* __restrict__ wsBS,
    unsigned short* __restrict__ routed)
{
    __shared__ unsigned short smem[65536];

    const int tid = threadIdx.x;
    const int l = (blockIdx.x & 7) * 128 + (blockIdx.x >> 3);
    const int bm = l >> 2, bn = l & 3;
    const int m0 = bm * 256, n0 = bn * 256;

    const int wid = tid >> 6, lane = tid & 63;
    const int ah = wid >> 2;
    const int bq = wid & 3;
    const int bh = bq >> 1;
    const int bo = (bq & 1) * 64;
    const int lr = lane & 15, kq = lane >> 4;
    const int lane8 = lane >> 3;
    const int c8s = ((lane & 7) ^ lane8) * 8;
    const int sw = lr & 7;

    f32x4 acc[8][4];
#pragma unroll
    for (int i = 0; i < 8; i++)
#pragma unroll
        for (int j = 0; j < 4; j++) acc[i][j] = (f32x4)0.0f;

#define STG_A1(db, h, t)                                                       \
    { const int _k0 = (t) * 64;                                                \
      _Pragma("unroll")                                                        \
      for (int q = 0; q < 2; ++q) {                                            \
          const int chunk = q * 8 + wid;                                       \
          gload16(xb + (size_t)(m0 + (h)*128 + chunk*8 + lane8) * H + _k0 + c8s,\
                  &ASP(db, h)[chunk * 512]);                                   \
      } }
#define STG_B1(db, h, t)                                                       \
    { const int _k0 = (t) * 64;                                                \
      _Pragma("unroll")                                                        \
      for (int q = 0; q < 2; ++q) {                                            \
          const int chunk = q * 8 + wid;                                       \
          gload16(Wr + (size_t)(n0 + (h)*128 + chunk*8 + lane8) * H + _k0 + c8s,\
                  &BSP(db, h)[chunk * 512]);                                   \
      } }

    STG_A1(0,0,0); STG_A1(0,1,0); STG_B1(0,0,0); STG_B1(0,1,0);
    STG_A1(1,0,1); STG_A1(1,1,1); STG_B1(1,0,1); STG_B1(1,1,1);
    asm volatile("s_waitcnt vmcnt(8)" ::: "memory");
    SB0();
    BAR();

    short8 Af[4][2], Bf0[2][2], Bf1[2][2];

    for (int t = 0; t < 16; ++t) {
        const int d = t & 1;
        const bool sA = (t > 0) && (t + 1 < 16);
        const bool sB = (t + 2 < 16);
        RD_A(0); RD_B(Bf0, 0);
        if (sA) { STG_A1(d^1, 0, t+1); }
        BAR(); WLG(); SB0();
        MMQ(Bf0, 0, 0);
        BAR();
        RD_B(Bf1, 32);
        if (sA) { STG_A1(d^1, 1, t+1); }
        BAR(); WLG(); SB0();
        MMQ(Bf1, 0, 2);
        BAR();
        RD_A(64);
        if (sB) { STG_B1(d, 0, t+2); }
        BAR(); WLG(); SB0();
        MMQ(Bf0, 4, 0);
        BAR();
        if (sB) { STG_B1(d, 1, t+2); }
        BAR(); SB0();
        MMQ(Bf1, 4, 2);
        if (sB)              { asm volatile("s_waitcnt vmcnt(4)" ::: "memory"); }
        else if (t + 1 < 16) { asm volatile("s_waitcnt vmcnt(0)" ::: "memory"); }
        SB0();
        BAR();
    }
#undef STG_A1
#undef STG_B1

    const int lowbit = kq & 1;
    float rc[4][8];
#pragma unroll
    for (int e = 0; e < 4; e++)
#pragma unroll
        for (int jj = 0; jj < 8; jj++) rc[e][jj] = wsR[(lowbit*4 + e)*8 + jj];
    float bsc[4];
#pragma unroll
    for (int e = 0; e < 4; e++) bsc[e] = wsBS[lowbit*4 + e];

#pragma unroll
    for (int mf = 0; mf < 8; ++mf) {
        const int lrow = ah*128 + mf*16 + kq*4;
#pragma unroll
        for (int nf = 0; nf < 4; ++nf) {
            const int lcol = bq*64 + nf*16 + lr;
            const float brv = b_route[n0 + lcol];
            float own[4], oth[4];
#pragma unroll
            for (int e = 0; e < 4; e++) {
                own[e] = acc[mf][nf][e];
                oth[e] = __shfl_xor(own[e], 16, 64);
            }
            float g8[8];
#pragma unroll
            for (int e = 0; e < 4; e++) {
                if (lowbit == 0) { g8[e] = own[e]; g8[4+e] = oth[e]; }
                else             { g8[e] = oth[e]; g8[4+e] = own[e]; }
            }
#pragma unroll
            for (int e = 0; e < 4; e++) {
                float m = 0.0f;
#pragma unroll
                for (int jj = 0; jj < 8; jj++) m += rc[e][jj] * g8[jj];
                m += bsc[e] * brv;
                smem[(lrow + e) * 256 + lcol] = f2bf(m);
            }
        }
    }
    __syncthreads();

    // coalesced non-temporal write of routed (keep L2 clean for pass 2)
    for (int r = wid; r < 256; r += 8) {
        const u16x4 v = *reinterpret_cast<const u16x4*>(&smem[r*256 + lane*4]);
        __builtin_nontemporal_store(v,
            reinterpret_cast<u16x4*>(&routed[(size_t)(m0 + r) * H + n0 + lane*4]));
    }
}

// pass 2: out = g*routed + (1-g)*x,  g = sigmoid([xb|routed] @ Wg^T + b)
__global__ __launch_bounds__(512, 2) void k_p2b(
    const unsigned short* __restrict__ xb,
    const unsigned short* __restrict__ Wg,
    const float* __restrict__ b_gate,
    const unsigned short* __restrict__ routed,
    float* __restrict__ out)
{
    __shared__ unsigned short smem[65536];

    const int tid = threadIdx.x;
    const int l = (blockIdx.x & 7) * 128 + (blockIdx.x >> 3);
    const int bm = l >> 2, bn = l & 3;
    const int m0 = bm * 256, n0 = bn * 256;

    const int wid = tid >> 6, lane = tid & 63;
    const int ah = wid >> 2;
    const int bq = wid & 3, bh = bq >> 1, bo = (bq & 1) * 64;
    const int lr = lane & 15, kq = lane >> 4;
    const int lane8 = lane >> 3;
    const int c8s = ((lane & 7) ^ lane8) * 8;
    const int sw = lr & 7;

    f32x4 acc[8][4];
#pragma unroll
    for (int i = 0; i < 8; i++)
#pragma unroll
        for (int j = 0; j < 4; j++) acc[i][j] = (f32x4)0.0f;

#define STG_A2(db, h, t)                                                       \
    { const int _k0 = (t) * 64;                                                \
      const unsigned short* _sb = (_k0 < H) ? xb : routed;                     \
      const int _kk = (_k0 < H) ? _k0 : (_k0 - H);                             \
      _Pragma("unroll")                                                        \
      for (int q = 0; q < 2; ++q) {                                            \
          const int chunk = q * 8 + wid;                                       \
          gload16(_sb + (size_t)(m0 + (h)*128 + chunk*8 + lane8) * H + _kk + c8s,\
                  &ASP(db, h)[chunk * 512]);                                   \
      } }
#define STG_B2(db, h, t)                                                       \
    { const int _k0 = (t) * 64;                                                \
      _Pragma("unroll")                                                        \
      for (int q = 0; q < 2; ++q) {                                            \
          const int chunk = q * 8 + wid;                                       \
          gload16(Wg + (size_t)(n0 + (h)*128 + chunk*8 + lane8) * H2 + _k0 + c8s,\
                  &BSP(db, h)[chunk * 512]);                                   \
      } }

    STG_A2(0,0,0); STG_A2(0,1,0); STG_B2(0,0,0); STG_B2(0,1,0);
    STG_A2(1,0,1); STG_A2(1,1,1); STG_B2(1,0,1); STG_B2(1,1,1);
    asm volatile("s_waitcnt vmcnt(8)" ::: "memory");
    SB0();
    BAR();

    short8 Af[4][2], Bf0[2][2], Bf1[2][2];

    for (int t = 0; t < 32; ++t) {
        const int d = t & 1;
        const bool sA = (t > 0) && (t + 1 < 32);
        const bool sB = (t + 2 < 32);
        RD_A(0); RD_B(Bf0, 0);
        if (sA) { STG_A2(d^1, 0, t+1); }
        BAR(); WLG(); SB0();
        MMQ(Bf0, 0, 0);
        BAR();
        RD_B(Bf1, 32);
        if (sA) { STG_A2(d^1, 1, t+1); }
        BAR(); WLG(); SB0();
        MMQ(Bf1, 0, 2);
        BAR();
        RD_A(64);
        if (sB) { STG_B2(d, 0, t+2); }
        BAR(); WLG(); SB0();
        MMQ(Bf0, 4, 0);
        BAR();
        if (sB) { STG_B2(d, 1, t+2); }
        BAR(); SB0();
        MMQ(Bf1, 4, 2);
        if (sB)              { asm volatile("s_waitcnt vmcnt(4)" ::: "memory"); }
        else if (t + 1 < 32) { asm volatile("s_waitcnt vmcnt(0)" ::: "memory"); }
        SB0();
        BAR();
    }
#undef STG_A2
#undef STG_B2

#pragma unroll
    for (int mf = 0; mf < 8; ++mf) {
        const int lrow = ah*128 + mf*16 + kq*4;
#pragma unroll
        for (int nf = 0; nf < 4; ++nf) {
            const int lcol = bq*64 + nf*16 + lr;
            const float bg = b_gate[n0 + lcol];
#pragma unroll
            for (int e = 0; e < 4; e++) {
                const float tt = acc[mf][nf][e] + bg;
                const float g = 1.0f / (1.0f + expf(-tt));
                smem[(lrow + e) * 256 + lcol] = f2bf(g);
            }
        }
    }
    __syncthreads();

    // coalesced blend sweep; nt loads (no L2 pollution) + nt store (stream)
    for (int r = wid; r < 256; r += 8) {
        const size_t grow = (size_t)(m0 + r) * H + n0 + lane*4;
        const u16x4 gv = *reinterpret_cast<const u16x4*>(&smem[r*256 + lane*4]);
        const u16x4 rv = __builtin_nontemporal_load(
            reinterpret_cast<const u16x4*>(&routed[grow]));
        const u16x4 xv = __builtin_nontemporal_load(
            reinterpret_cast<const u16x4*>(&xb[grow]));
        f32x4 o;
#pragma unroll
        for (int e = 0; e < 4; e++) {
            const float gg = bf2f(gv[e]);
            o[e] = gg * bf2f(rv[e]) + (1.0f - gg) * bf2f(xv[e]);
        }
        __builtin_nontemporal_store(o, reinterpret_cast<f32x4*>(&out[grow]));
    }
}

// ---------------- fallback (small ws): fully fused, fp32 vector ----------------
__global__ __launch_bounds__(256) void k_fallback(
    const float* __restrict__ x, const float* __restrict__ Wr, const float* __restrict__ br,
    const float* __restrict__ Wg, const float* __restrict__ bg,
    const float* __restrict__ wsR, const float* __restrict__ wsBS,
    float* __restrict__ out)
{
    __shared__ float xs[8][H];
    __shared__ float rt[8][H];
    __shared__ float Rs[64];
    __shared__ float BSs[8];

    const int tid = threadIdx.x;
    const size_t base = (size_t)blockIdx.x * (8 * H);
    if (tid < 64) Rs[tid] = wsR[tid];
    if (tid < 8)  BSs[tid] = wsBS[tid];

#pragma unroll
    for (int it = 0; it < 8; ++it) {
        int s = it * 256 + tid;
        reinterpret_cast<float4*>(&xs[0][0])[s] = reinterpret_cast<const float4*>(x + base)[s];
    }
    __syncthreads();

    for (int eo = 0; eo < 4; ++eo) {
        int e = eo * 256 + tid;
        float acc[8];
#pragma unroll
        for (int l = 0; l < 8; l++) acc[l] = 0.0f;
        const float* w = Wr + (size_t)e * H;
        for (int k = 0; k < H; k += 4) {
            float4 wv = *reinterpret_cast<const float4*>(w + k);
#pragma unroll
            for (int l = 0; l < 8; l++)
                acc[l] += wv.x * xs[l][k] + wv.y * xs[l][k+1] + wv.z * xs[l][k+2] + wv.w * xs[l][k+3];
        }
        float brv = br[e];
#pragma unroll
        for (int l = 0; l < 8; l++) {
            float m = 0.0f;
#pragma unroll
            for (int j = 0; j < 8; j++) m += Rs[l*8 + j] * acc[j];
            rt[l][e] = m + BSs[l] * brv;
        }
    }
    __syncthreads();

    for (int eo = 0; eo < 4; ++eo) {
        int e = eo * 256 + tid;
        float acc2[8];
#pragma unroll
        for (int l = 0; l < 8; l++) acc2[l] = 0.0f;
        const float* w1 = Wg + (size_t)e * (2 * H);
        for (int k = 0; k < H; k += 4) {
            float4 wv = *reinterpret_cast<const float4*>(w1 + k);
#pragma unroll
            for (int l = 0; l < 8; l++)
                acc2[l] += wv.x * xs[l][k] + wv.y * xs[l][k+1] + wv.z * xs[l][k+2] + wv.w * xs[l][k+3];
        }
        const float* w2 = w1 + H;
        for (int k = 0; k < H; k += 4) {
            float4 wv = *reinterpret_cast<const float4*>(w2 + k);
#pragma unroll
            for (int l = 0; l < 8; l++)
                acc2[l] += wv.x * rt[l][k] + wv.y * rt[l][k+1] + wv.z * rt[l][k+2] + wv.w * rt[l][k+3];
        }
        float bgv = bg[e];
#pragma unroll
        for (int l = 0; l < 8; l++) {
            float t = acc2[l] + bgv;
            float g = 1.0f / (1.0f + expf(-t));
            out[base + (size_t)l * H + e] = g * rt[l][e] + (1.0f - g) * xs[l][e];
        }
    }
}

extern "C" void kernel_launch(void* const* d_in, const int* in_sizes, int n_in,
                              void* d_out, int out_size, void* d_ws, size_t ws_size,
                              hipStream_t stream) {
    const float* x   = (const float*)d_in[0];
    const float* lp  = (const float*)d_in[1];
    const float* thr = (const float*)d_in[2];
    const float* Wr  = (const float*)d_in[3];
    const float* br  = (const float*)d_in[4];
    const float* Wg  = (const float*)d_in[5];
    const float* bg  = (const float*)d_in[6];
    float* out = (float*)d_out;
    char* ws = (char*)d_ws;

    float* wsR  = (float*)(ws + WS_R_OFF);
    float* wsBS = (float*)(ws + WS_BS_OFF);

    k_routing<<<1, 64, 0, stream>>>(lp, thr, wsR, wsBS);

    if (ws_size >= WS_NEED_FULL) {
        unsigned short* wsWr = (unsigned short*)(ws + WS_WR_OFF);
        unsigned short* wsWg = (unsigned short*)(ws + WS_WG_OFF);
        unsigned short* wsRt = (unsigned short*)(ws + WS_RT_OFF);
        unsigned short* wsXb = (unsigned short*)(ws + WS_XB_OFF);
        k_f32_to_bf16<<<512, 256, 0, stream>>>(Wr, wsWr, (1024 * 1024) / 4);
        k_f32_to_bf16<<<1024, 256, 0, stream>>>(Wg, wsWg, (1024 * 2048) / 4);
        k_f32_to_bf16<<<4096, 256, 0, stream>>>(x, wsXb, (MTOK * H) / 4);
        k_p1b<<<(MTOK / 256) * (H / 256), 512, 0, stream>>>(wsXb, wsWr, br, wsR, wsBS, wsRt);
        k_p2b<<<(MTOK / 256) * (H / 256), 512, 0, stream>>>(wsXb, wsWg, bg, wsRt, out);
    } else {
        k_fallback<<<MTOK / 8, 256, 0, stream>>>(x, Wr, br, Wg, bg, wsR, wsBS, out);
    }
}